// Round 5
// baseline (327.316 us; speedup 1.0000x reference)
//
#include <hip/hip_runtime.h>

// Problem constants (from reference setup_inputs)
#define N_ 8
#define T_ 200
#define U_ 50
#define V_ 500
#define NTU (N_ * T_ * U_)          // 80,000 rows
#define EPSF 1e-10f

#define ROWS 16                      // rows per block
#define ROWF (ROWS * V_)             // 8000 floats = 32000 B per tensor per block
#define FULLC 31                     // 31 full 1KB DMA chunks; tail = 256 B

// R4b (rerun of R4 after infra failure): DUAL-PATH experiment.
// R0-R2 (register-return path) and R3 (LDS-DMA path) EACH pin at 2.83 TB/s
// delivered (320MB/114us), insensitive to schedule, occupancy (19%-76%),
// and batching. Two live theories:
//  (A) per-CU per-path request-tracker cap -> splitting the two tensors
//      across BOTH paths simultaneously ~doubles delivered BW;
//  (B) shared per-direction fabric read cap (~3.15 TB/s, read half of the
//      m13 copy ubench) -> no change, and that is the roofline.
// Student tensor (lg) -> LDS via global_load_lds DMA.
// Teacher tensor (tl) -> VGPRs via float4 loads, pinned live with
// asm volatile("" : "+v"(scalar)) so IR-level load sinking (which defeated
// R1/R2, proven by VGPR_Count=40) cannot re-serialize the batch.
__global__ __launch_bounds__(256) void tkd_kernel(
    const float* __restrict__ lg,    // student logits (N,T,U,V) fp32
    const float* __restrict__ tl,    // teacher logits (N,T,U,V) fp32
    const int* __restrict__ y,       // (N,U) int32
    const int* __restrict__ xlen,    // (N,) int32
    const int* __restrict__ ylen,    // (N,) int32
    float* __restrict__ out)         // (2,N,T,U,3) fp32
{
    __shared__ float bufA[ROWF];

    const int tid  = threadIdx.x;
    const int wv   = tid >> 6;        // wave 0..3
    const int ln   = tid & 63;        // lane in wave
    const int row0 = blockIdx.x * ROWS;

    // ---- per-group row bookkeeping ----
    const int g   = tid >> 4;         // group 0..15 -> one row each
    const int l   = tid & 15;         // lane in group
    const int row = row0 + g;
    const int n   = row / (T_ * U_);
    const int r2  = row - n * (T_ * U_);
    const int t   = r2 / U_;
    const int u   = r2 - t * U_;
    const int yv  = y[n * U_ + u];    // in [1, V)

    // ---- path 1: teacher bulk -> VGPRs (8 float4 per lane, interleaved) ----
    const size_t base = (size_t)row * V_;
    const float4* pb  = reinterpret_cast<const float4*>(tl + base);
    const int ltail   = (l <= 12) ? l : 12;
    float4 B0 = pb[0 * 16 + l];
    float4 B1 = pb[1 * 16 + l];
    float4 B2 = pb[2 * 16 + l];
    float4 B3 = pb[3 * 16 + l];
    float4 B4 = pb[4 * 16 + l];
    float4 B5 = pb[5 * 16 + l];
    float4 B6 = pb[6 * 16 + l];
    float4 B7 = pb[112 + ltail];

    // teacher selected elements (their lines are already inbound -> cache hits)
    const float by = tl[base + yv];
    const float b0 = tl[base];

    // ---- path 2: student bulk -> LDS via DMA (8 chunks per wave) ----
    const float* gA = lg + (size_t)row0 * V_;   // 32000 B contiguous per block
#pragma unroll
    for (int c = wv; c < FULLC; c += 4) {
        __builtin_amdgcn_global_load_lds(
            (const __attribute__((address_space(1))) void*)(gA + c * 256 + ln * 4),
            (__attribute__((address_space(3))) void*)(&bufA[c * 256 + ln * 4]),
            16, 0, 0);
    }
    if (wv == 3) {
        __builtin_amdgcn_global_load_lds(
            (const __attribute__((address_space(1))) void*)(gA + 7936 + ln),
            (__attribute__((address_space(3))) void*)(&bufA[7936 + ln]),
            4, 0, 0);
    }

    // ---- unpack teacher components and pin them live (forces the batch) ----
    float b00 = B0.x, b01 = B0.y, b02 = B0.z, b03 = B0.w;
    float b04 = B1.x, b05 = B1.y, b06 = B1.z, b07 = B1.w;
    float b08 = B2.x, b09 = B2.y, b10 = B2.z, b11 = B2.w;
    float b12 = B3.x, b13 = B3.y, b14 = B3.z, b15 = B3.w;
    float b16 = B4.x, b17 = B4.y, b18 = B4.z, b19 = B4.w;
    float b20 = B5.x, b21 = B5.y, b22 = B5.z, b23 = B5.w;
    float b24 = B6.x, b25 = B6.y, b26 = B6.z, b27 = B6.w;
    float b28 = B7.x, b29 = B7.y, b30 = B7.z, b31 = B7.w;
    asm volatile("" : "+v"(b00), "+v"(b01), "+v"(b02), "+v"(b03),
                      "+v"(b04), "+v"(b05), "+v"(b06), "+v"(b07));
    asm volatile("" : "+v"(b08), "+v"(b09), "+v"(b10), "+v"(b11),
                      "+v"(b12), "+v"(b13), "+v"(b14), "+v"(b15));
    asm volatile("" : "+v"(b16), "+v"(b17), "+v"(b18), "+v"(b19),
                      "+v"(b20), "+v"(b21), "+v"(b22), "+v"(b23));
    asm volatile("" : "+v"(b24), "+v"(b25), "+v"(b26), "+v"(b27),
                      "+v"(b28), "+v"(b29), "+v"(b30), "+v"(b31));

    // ---- consume teacher from registers (DMAs still in flight) ----
    const float wmask = (l <= 12) ? 1.0f : 0.0f;
    float sB = 0.f;
    sB += __expf(b00) + __expf(b01) + __expf(b02) + __expf(b03);
    sB += __expf(b04) + __expf(b05) + __expf(b06) + __expf(b07);
    sB += __expf(b08) + __expf(b09) + __expf(b10) + __expf(b11);
    sB += __expf(b12) + __expf(b13) + __expf(b14) + __expf(b15);
    sB += __expf(b16) + __expf(b17) + __expf(b18) + __expf(b19);
    sB += __expf(b20) + __expf(b21) + __expf(b22) + __expf(b23);
    sB += __expf(b24) + __expf(b25) + __expf(b26) + __expf(b27);
    sB += wmask * (__expf(b28) + __expf(b29) + __expf(b30) + __expf(b31));
#pragma unroll
    for (int off = 1; off < 16; off <<= 1) sB += __shfl_xor(sB, off, 64);

    // ---- wait DMA completion, then consume student from LDS ----
    asm volatile("s_waitcnt vmcnt(0)" ::: "memory");
    __builtin_amdgcn_s_barrier();
    asm volatile("" ::: "memory");

    const float* ra = &bufA[g * V_];
    float sA = 0.f;
#pragma unroll
    for (int j = 0; j < 7; ++j) {
        const float4 v = *reinterpret_cast<const float4*>(ra + (j * 16 + l) * 4);
        sA += __expf(v.x) + __expf(v.y) + __expf(v.z) + __expf(v.w);
    }
    {
        const float4 v = *reinterpret_cast<const float4*>(ra + (112 + ltail) * 4);
        sA += wmask * (__expf(v.x) + __expf(v.y) + __expf(v.z) + __expf(v.w));
    }
#pragma unroll
    for (int off = 1; off < 16; off <<= 1) sA += __shfl_xor(sA, off, 64);
    const float ay = ra[yv];
    const float a0 = ra[0];

    if (l == 0) {
        const float invA = 1.0f / sA;
        const float invB = 1.0f / sB;
        const float py   = __expf(ay) * invA;
        const float pbl  = __expf(a0) * invA;
        const float prem = 1.0f - py - pbl;
        const float tpy  = __expf(by) * invB;
        const float tbl  = __expf(b0) * invB;
        float trem = 1.0f - tpy - tbl;
        if (trem < 0.0f) trem = EPSF;

        // student = log(clip(p, EPS, 1))
        const float s0 = __logf(fminf(fmaxf(py,   EPSF), 1.0f));
        const float s1 = __logf(fminf(fmaxf(pbl,  EPSF), 1.0f));
        const float s2 = __logf(fminf(fmaxf(prem, EPSF), 1.0f));

        const float mm = ((t < xlen[n]) && (u < ylen[n])) ? 1.0f : 0.0f;

        const size_t o = (size_t)row * 3;
        out[o + 0] = s0 * mm;
        out[o + 1] = s1 * mm;
        out[o + 2] = s2 * mm;
        const size_t o2 = (size_t)NTU * 3 + o;
        out[o2 + 0] = tpy  * mm;
        out[o2 + 1] = tbl  * mm;
        out[o2 + 2] = trem * mm;
    }
}

extern "C" void kernel_launch(void* const* d_in, const int* in_sizes, int n_in,
                              void* d_out, int out_size, void* d_ws, size_t ws_size,
                              hipStream_t stream) {
    const float* lg = (const float*)d_in[0];
    const float* tl = (const float*)d_in[1];
    const int* y    = (const int*)d_in[2];
    const int* xlen = (const int*)d_in[3];
    const int* ylen = (const int*)d_in[4];
    float* out = (float*)d_out;

    // 80,000 rows / 16 rows per block -> exactly 5,000 blocks of 256 threads
    tkd_kernel<<<NTU / ROWS, 256, 0, stream>>>(lg, tl, y, xlen, ylen, out);
}

// Round 6
// 325.642 us; speedup vs baseline: 1.0051x; 1.0051x over previous
//
#include <hip/hip_runtime.h>

// Problem constants (from reference setup_inputs)
#define N_ 8
#define T_ 200
#define U_ 50
#define V_ 500
#define NTU (N_ * T_ * U_)          // 80,000 rows
#define EPSF 1e-10f

#define BLOCKS   1024
#define GROUPS   (BLOCKS * 16)       // 16,384 16-lane groups, grid-stride over rows

// R5: PERSISTENT grid-stride structure (the m13 copy-bench shape).
// R0-R4 established a rate-limited read path: delivered read BW pins at
// ~2.83 TB/s (11 GB/s/CU) across 4 mechanisms while in-flight bytes varied
// 50x -> queuing, not latency. The only structural difference vs the m13
// reference (3.15 TB/s read-half) is wave churn: one-shot waves drain to
// zero and die (250K launches). This version keeps waves resident (4
// blocks/CU), each 16-lane group looping rows at stride GROUPS, issuing
// loads continuously. A-consume overlaps B-flight within each iteration.
__global__ __launch_bounds__(256) void tkd_kernel(
    const float* __restrict__ lg,    // student logits (N,T,U,V) fp32
    const float* __restrict__ tl,    // teacher logits (N,T,U,V) fp32
    const int* __restrict__ y,       // (N,U) int32
    const int* __restrict__ xlen,    // (N,) int32
    const int* __restrict__ ylen,    // (N,) int32
    float* __restrict__ out)         // (2,N,T,U,3) fp32
{
    const int tid = threadIdx.x;
    const int l   = tid & 15;                        // lane within 16-lane group
    const int g0  = blockIdx.x * 16 + (tid >> 4);    // global group id
    const int ltail = (l <= 12) ? l : 12;
    const float wmask = (l <= 12) ? 1.0f : 0.0f;

    for (int row = g0; row < NTU; row += GROUPS) {
        const int n  = row / (T_ * U_);
        const int r2 = row - n * (T_ * U_);
        const int t  = r2 / U_;
        const int u  = r2 - t * U_;

        const size_t base = (size_t)row * V_;        // 16B-aligned (V_*4 = 2000)
        const float4* pa = reinterpret_cast<const float4*>(lg + base);
        const float4* pb = reinterpret_cast<const float4*>(tl + base);

        // ---- issue A then B loads; consume A while B is still in flight ----
        float4 A[8], B[8];
#pragma unroll
        for (int j = 0; j < 7; ++j) A[j] = pa[j * 16 + l];
        A[7] = pa[112 + ltail];
#pragma unroll
        for (int j = 0; j < 7; ++j) B[j] = pb[j * 16 + l];
        B[7] = pb[112 + ltail];

        const int yv = y[n * U_ + u];                // in [1, V)

        float sA = 0.f;
#pragma unroll
        for (int j = 0; j < 7; ++j) {
            sA += __expf(A[j].x) + __expf(A[j].y) + __expf(A[j].z) + __expf(A[j].w);
        }
        sA += wmask * (__expf(A[7].x) + __expf(A[7].y) + __expf(A[7].z) + __expf(A[7].w));

        float sB = 0.f;
#pragma unroll
        for (int j = 0; j < 7; ++j) {
            sB += __expf(B[j].x) + __expf(B[j].y) + __expf(B[j].z) + __expf(B[j].w);
        }
        sB += wmask * (__expf(B[7].x) + __expf(B[7].y) + __expf(B[7].z) + __expf(B[7].w));

        // ---- 16-lane allreduce, two independent chains ----
#pragma unroll
        for (int off = 1; off < 16; off <<= 1) {
            sA += __shfl_xor(sA, off, 64);
            sB += __shfl_xor(sB, off, 64);
        }

        // ---- selected elements (lines just fetched by this group -> L1 hits) ----
        const float ay = lg[base + yv];
        const float by = tl[base + yv];
        const float a0 = lg[base];
        const float b0 = tl[base];

        if (l == 0) {
            const float invA = 1.0f / sA;
            const float invB = 1.0f / sB;
            const float py   = __expf(ay) * invA;
            const float pbl  = __expf(a0) * invA;
            const float prem = 1.0f - py - pbl;
            const float tpy  = __expf(by) * invB;
            const float tbl  = __expf(b0) * invB;
            float trem = 1.0f - tpy - tbl;
            if (trem < 0.0f) trem = EPSF;

            // student = log(clip(p, EPS, 1))
            const float s0 = __logf(fminf(fmaxf(py,   EPSF), 1.0f));
            const float s1 = __logf(fminf(fmaxf(pbl,  EPSF), 1.0f));
            const float s2 = __logf(fminf(fmaxf(prem, EPSF), 1.0f));

            const float mm = ((t < xlen[n]) && (u < ylen[n])) ? 1.0f : 0.0f;

            const size_t o = (size_t)row * 3;
            out[o + 0] = s0 * mm;
            out[o + 1] = s1 * mm;
            out[o + 2] = s2 * mm;
            const size_t o2 = (size_t)NTU * 3 + o;
            out[o2 + 0] = tpy  * mm;
            out[o2 + 1] = tbl  * mm;
            out[o2 + 2] = trem * mm;
        }
    }
}

extern "C" void kernel_launch(void* const* d_in, const int* in_sizes, int n_in,
                              void* d_out, int out_size, void* d_ws, size_t ws_size,
                              hipStream_t stream) {
    const float* lg = (const float*)d_in[0];
    const float* tl = (const float*)d_in[1];
    const int* y    = (const int*)d_in[2];
    const int* xlen = (const int*)d_in[3];
    const int* ylen = (const int*)d_in[4];
    float* out = (float*)d_out;

    // Persistent-ish: 1024 blocks (4 per CU), 16-lane groups grid-stride rows
    tkd_kernel<<<BLOCKS, 256, 0, stream>>>(lg, tl, y, xlen, ylen, out);
}

// Round 8
// 319.293 us; speedup vs baseline: 1.0251x; 1.0199x over previous
//
#include <hip/hip_runtime.h>

// Problem constants (from reference setup_inputs)
#define N_ 8
#define T_ 200
#define U_ 50
#define V_ 500
#define NTU (N_ * T_ * U_)          // 80,000 rows
#define EPSF 1e-10f

// R6 (resubmitted after infra failure): exact m13-copy load SHAPE — the one
// untested variable.
// R0-R5: delivered reads pin at 2.87 TB/s across one-shot/persistent,
// reg-return/LDS-DMA/dual-path, occupancy 19-76%, in-flight 5KB-240KB.
// Remaining structural difference vs the m13 reference (3.15 TB/s read-half):
// per-instruction contiguity. Here each wave owns one row and lane l loads
// float4 l (bytes [0,1024) contiguous) then float4 64+l (bytes [1024,2000)
// contiguous); consecutive waves sweep consecutive rows -> pure linear
// stream, maximally compact per instruction. Single-variable change vs R0
// (which interleaved float4s 2i/2i+1 at 50% density per instruction).
__global__ __launch_bounds__(256) void tkd_kernel(
    const float* __restrict__ lg,    // student logits (N,T,U,V) fp32
    const float* __restrict__ tl,    // teacher logits (N,T,U,V) fp32
    const int* __restrict__ y,       // (N,U) int32
    const int* __restrict__ xlen,    // (N,) int32
    const int* __restrict__ ylen,    // (N,) int32
    float* __restrict__ out)         // (2,N,T,U,3) fp32
{
    const int wid  = (int)((blockIdx.x * 256 + threadIdx.x) >> 6);  // row id
    const int lane = threadIdx.x & 63;
    if (wid >= NTU) return;

    const int n  = wid / (T_ * U_);
    const int r2 = wid - n * (T_ * U_);
    const int t  = r2 / U_;
    const int u  = r2 - t * U_;

    const size_t base = (size_t)wid * V_;            // 16B-aligned (V_*4 = 2000)
    const float4* pa = reinterpret_cast<const float4*>(lg + base);
    const float4* pb = reinterpret_cast<const float4*>(tl + base);

    // Row = 125 float4s. Instr 1: float4 l (l=0..63, fully dense 1024 B).
    // Instr 2: float4 64+l, valid for l<=60 (float4s 64..124, dense 976 B);
    // lanes 61..63 clamp to 124 and are masked out of the sum.
    const int   l2    = 64 + ((lane <= 60) ? lane : 60);
    const float wmask = (lane <= 60) ? 1.0f : 0.0f;

    const float4 A1 = pa[lane];
    const float4 A2 = pa[l2];
    const float4 B1 = pb[lane];
    const float4 B2 = pb[l2];

    const int yv = y[n * U_ + u];                    // in [1, V), wave-uniform

    // ---- per-lane sum of exp ----
    float sA = __expf(A1.x) + __expf(A1.y) + __expf(A1.z) + __expf(A1.w);
    sA += wmask * (__expf(A2.x) + __expf(A2.y) + __expf(A2.z) + __expf(A2.w));
    float sB = __expf(B1.x) + __expf(B1.y) + __expf(B1.z) + __expf(B1.w);
    sB += wmask * (__expf(B2.x) + __expf(B2.y) + __expf(B2.z) + __expf(B2.w));

    // ---- wave allreduce (64 lanes), two independent chains ----
#pragma unroll
    for (int off = 32; off > 0; off >>= 1) {
        sA += __shfl_xor(sA, off, 64);
        sB += __shfl_xor(sB, off, 64);
    }

    // ---- selected elements: lines just fetched by this wave -> cache hits ----
    const float ay = lg[base + yv];
    const float by = tl[base + yv];
    const float a0 = lg[base];
    const float b0 = tl[base];

    if (lane == 0) {
        const float invA = 1.0f / sA;
        const float invB = 1.0f / sB;
        const float py   = __expf(ay) * invA;
        const float pbl  = __expf(a0) * invA;
        const float prem = 1.0f - py - pbl;
        const float tpy  = __expf(by) * invB;
        const float tbl  = __expf(b0) * invB;
        float trem = 1.0f - tpy - tbl;
        if (trem < 0.0f) trem = EPSF;

        // student = log(clip(p, EPS, 1))
        const float s0 = __logf(fminf(fmaxf(py,   EPSF), 1.0f));
        const float s1 = __logf(fminf(fmaxf(pbl,  EPSF), 1.0f));
        const float s2 = __logf(fminf(fmaxf(prem, EPSF), 1.0f));

        const float mm = ((t < xlen[n]) && (u < ylen[n])) ? 1.0f : 0.0f;

        const size_t o = (size_t)wid * 3;
        out[o + 0] = s0 * mm;
        out[o + 1] = s1 * mm;
        out[o + 2] = s2 * mm;
        const size_t o2 = (size_t)NTU * 3 + o;
        out[o2 + 0] = tpy  * mm;
        out[o2 + 1] = tbl  * mm;
        out[o2 + 2] = trem * mm;
    }
}

extern "C" void kernel_launch(void* const* d_in, const int* in_sizes, int n_in,
                              void* d_out, int out_size, void* d_ws, size_t ws_size,
                              hipStream_t stream) {
    const float* lg = (const float*)d_in[0];
    const float* tl = (const float*)d_in[1];
    const int* y    = (const int*)d_in[2];
    const int* xlen = (const int*)d_in[3];
    const int* ylen = (const int*)d_in[4];
    float* out = (float*)d_out;

    // 80,000 rows, 1 wave each, 4 waves per 256-thread block -> 20,000 blocks
    const int blocks = (NTU + 3) / 4;
    tkd_kernel<<<blocks, 256, 0, stream>>>(lg, tl, y, xlen, ylen, out);
}